// Round 1
// baseline (364.462 us; speedup 1.0000x reference)
//
#include <hip/hip_runtime.h>

#define LEAK 0.2f

static inline size_t align256(size_t x) { return (x + 255) & ~size_t(255); }

// ---------------- CSR build ----------------
__global__ void k_count(const int* __restrict__ edst, int E, int N, int* __restrict__ deg) {
    int total = E + N;
    for (int k = blockIdx.x * blockDim.x + threadIdx.x; k < total; k += gridDim.x * blockDim.x) {
        int d = (k < E) ? edst[k] : (k - E);
        atomicAdd(&deg[d], 1);
    }
}

// single-block exclusive scan: rowptr[0]=0, rowptr[i+1]=rowptr[i]+deg[i]
__global__ void k_scan(const int* __restrict__ deg, int N, int* __restrict__ rowptr) {
    __shared__ int buf[1024];
    __shared__ int carry_s;
    int tid = threadIdx.x;
    if (tid == 0) { carry_s = 0; rowptr[0] = 0; }
    __syncthreads();
    for (int base = 0; base < N; base += 1024) {
        int i = base + tid;
        int v = (i < N) ? deg[i] : 0;
        buf[tid] = v;
        __syncthreads();
        for (int off = 1; off < 1024; off <<= 1) {
            int t = buf[tid];
            int add = (tid >= off) ? buf[tid - off] : 0;
            __syncthreads();
            buf[tid] = t + add;
            __syncthreads();
        }
        int incl = buf[tid];
        int carry = carry_s;
        if (i < N) rowptr[i + 1] = carry + incl;
        __syncthreads();
        if (tid == 1023) carry_s = carry + incl;
        __syncthreads();
    }
}

__global__ void k_scatter(const int* __restrict__ esrc, const int* __restrict__ edst,
                          int E, int N, const int* __restrict__ rowptr,
                          int* __restrict__ cursor, int* __restrict__ csr_src) {
    int total = E + N;
    for (int k = blockIdx.x * blockDim.x + threadIdx.x; k < total; k += gridDim.x * blockDim.x) {
        int s, d;
        if (k < E) { s = esrc[k]; d = edst[k]; } else { s = d = k - E; }
        int pos = atomicAdd(&cursor[d], 1);
        csr_src[rowptr[d] + pos] = s;
    }
}

// ---------------- GEMM: h[N,128] = x[N,128] @ W[128,128] ----------------
// block=256 threads, 32-row tile. W (64KB) + x-tile (16KB) in LDS -> 80KB, 2 blocks/CU.
__global__ __launch_bounds__(256) void k_gemm128(const float* __restrict__ x,
                                                 const float* __restrict__ W,
                                                 float* __restrict__ h, int N) {
    __shared__ float sW[128 * 128];
    __shared__ float sX[32 * 128];
    int tid = threadIdx.x;
    const float4* W4 = (const float4*)W;
    float4* sW4 = (float4*)sW;
#pragma unroll
    for (int i = 0; i < 16; ++i) sW4[tid + i * 256] = W4[tid + i * 256];

    int row0 = blockIdx.x * 32;
    int lr = tid >> 5;       // 0..7
    int lk = tid & 31;       // float4 index within row
    const float4* x4 = (const float4*)x;
    float4* sX4 = (float4*)sX;
#pragma unroll
    for (int i = 0; i < 4; ++i) {
        int r = lr + i * 8;
        int gr = row0 + r; if (gr > N - 1) gr = N - 1;
        sX4[r * 32 + lk] = x4[gr * 32 + lk];
    }
    __syncthreads();

    int tr = (tid >> 5) * 4;    // 4 rows
    int tc = (tid & 31) * 4;    // 4 cols
    float acc[4][4] = {};
#pragma unroll 4
    for (int k = 0; k < 128; ++k) {
        float4 w = *(const float4*)&sW[k * 128 + tc];
#pragma unroll
        for (int i = 0; i < 4; ++i) {
            float xv = sX[(tr + i) * 128 + k];
            acc[i][0] += xv * w.x; acc[i][1] += xv * w.y;
            acc[i][2] += xv * w.z; acc[i][3] += xv * w.w;
        }
    }
#pragma unroll
    for (int i = 0; i < 4; ++i) {
        int gr = row0 + tr + i;
        if (gr < N) {
            float4 o; o.x = acc[i][0]; o.y = acc[i][1]; o.z = acc[i][2]; o.w = acc[i][3];
            *(float4*)&h[gr * 128 + tc] = o;
        }
    }
}

// ---------------- alphas: as[i]=h[i].a_src, ad[i]=h[i].a_dst (one wave/node) ----------------
__global__ __launch_bounds__(256) void k_alpha128(const float* __restrict__ h,
                                                  const float* __restrict__ avs,
                                                  const float* __restrict__ avd,
                                                  float* __restrict__ as, float* __restrict__ ad, int N) {
    int wid = (blockIdx.x * blockDim.x + threadIdx.x) >> 6;
    int lane = threadIdx.x & 63;
    if (wid >= N) return;
    float h0 = h[wid * 128 + lane], h1 = h[wid * 128 + 64 + lane];
    float ps = h0 * avs[lane] + h1 * avs[64 + lane];
    float pd = h0 * avd[lane] + h1 * avd[64 + lane];
#pragma unroll
    for (int off = 32; off; off >>= 1) {
        ps += __shfl_xor(ps, off);
        pd += __shfl_xor(pd, off);
    }
    if (lane == 0) { as[wid] = ps; ad[wid] = pd; }
}

// ---------------- layer-1 aggregation (128 feats, one wave per dst node) ----------------
__global__ __launch_bounds__(256) void k_agg128(const float* __restrict__ h,
                                                const float* __restrict__ as,
                                                const float* __restrict__ ad,
                                                const float* __restrict__ bias,
                                                const int* __restrict__ rowptr,
                                                const int* __restrict__ csr_src,
                                                float* __restrict__ out, int N) {
    int wid = (blockIdx.x * blockDim.x + threadIdx.x) >> 6;
    int lane = threadIdx.x & 63;
    if (wid >= N) return;
    int start = rowptr[wid], end = rowptr[wid + 1];
    int deg = end - start;
    float adv = ad[wid];

    int s_l = 0; float e_l = -1e30f;
    if (lane < deg) {
        s_l = csr_src[start + lane];
        float e = as[s_l] + adv;
        e_l = e > 0.f ? e : LEAK * e;
    }
    float m = e_l;
    for (int j = start + 64 + lane; j < end; j += 64) {
        int s = csr_src[j];
        float e = as[s] + adv;
        e = e > 0.f ? e : LEAK * e;
        m = fmaxf(m, e);
    }
#pragma unroll
    for (int off = 32; off; off >>= 1) m = fmaxf(m, __shfl_xor(m, off));

    float acc0 = 0.f, acc1 = 0.f, denom = 0.f;
    int dmain = deg < 64 ? deg : 64;
    for (int j = 0; j < dmain; ++j) {
        int s = __shfl(s_l, j);
        float e = __shfl(e_l, j);
        float w = __expf(e - m);
        denom += w;
        acc0 += w * h[s * 128 + lane];
        acc1 += w * h[s * 128 + 64 + lane];
    }
    for (int j = start + 64; j < end; ++j) {
        int s = csr_src[j];  // wave-uniform
        float e = as[s] + adv;
        e = e > 0.f ? e : LEAK * e;
        float w = __expf(e - m);
        denom += w;
        acc0 += w * h[s * 128 + lane];
        acc1 += w * h[s * 128 + 64 + lane];
    }
    float inv = 1.0f / denom;
    float o0 = acc0 * inv + bias[lane];
    float o1 = acc1 * inv + bias[64 + lane];
    out[wid * 128 + lane]      = fmaxf(o0, 0.f);   // fused ReLU (layer 1)
    out[wid * 128 + 64 + lane] = fmaxf(o1, 0.f);
}

// ------- h2[N,16] = g[N,128] @ W2[128,16], fused alpha2 dots (one wave/node) -------
__global__ __launch_bounds__(256) void k_gemm16(const float* __restrict__ g,
                                                const float* __restrict__ W2,
                                                const float* __restrict__ avs,
                                                const float* __restrict__ avd,
                                                float* __restrict__ h2,
                                                float* __restrict__ as2, float* __restrict__ ad2, int N) {
    int wid = (blockIdx.x * blockDim.x + threadIdx.x) >> 6;
    int lane = threadIdx.x & 63;
    if (wid >= N) return;
    int col = lane & 15, kg = lane >> 4;   // 4 k-groups x 32
    float acc = 0.f;
#pragma unroll
    for (int kk = 0; kk < 32; ++kk) {
        int k = kg * 32 + kk;
        acc += g[wid * 128 + k] * W2[k * 16 + col];
    }
    acc += __shfl_xor(acc, 16);
    acc += __shfl_xor(acc, 32);          // all lanes: h2 value for their col
    if (lane < 16) h2[wid * 16 + col] = acc;
    float ps = acc * avs[col];
    float pd = acc * avd[col];
#pragma unroll
    for (int off = 8; off; off >>= 1) {
        ps += __shfl_xor(ps, off);
        pd += __shfl_xor(pd, off);
    }
    if (lane == 0) { as2[wid] = ps; ad2[wid] = pd; }
}

// ---------------- layer-2 aggregation (16 feats, edge-parallel per wave) ----------------
__global__ __launch_bounds__(256) void k_agg16(const float* __restrict__ h2,
                                               const float* __restrict__ as,
                                               const float* __restrict__ ad,
                                               const float* __restrict__ bias,
                                               const int* __restrict__ rowptr,
                                               const int* __restrict__ csr_src,
                                               float* __restrict__ out, int N) {
    int wid = (blockIdx.x * blockDim.x + threadIdx.x) >> 6;
    int lane = threadIdx.x & 63;
    if (wid >= N) return;
    int start = rowptr[wid], end = rowptr[wid + 1];
    float adv = ad[wid];

    int s_l = 0; float e_l = -1e30f;
    if (start + lane < end) {
        s_l = csr_src[start + lane];
        float e = as[s_l] + adv;
        e_l = e > 0.f ? e : LEAK * e;
    }
    float m = e_l;
    for (int j = start + 64 + lane; j < end; j += 64) {
        int s = csr_src[j];
        float e = as[s] + adv;
        e = e > 0.f ? e : LEAK * e;
        m = fmaxf(m, e);
    }
#pragma unroll
    for (int off = 32; off; off >>= 1) m = fmaxf(m, __shfl_xor(m, off));

    float acc[16];
#pragma unroll
    for (int f = 0; f < 16; ++f) acc[f] = 0.f;
    float dsum = 0.f;
    for (int j = start + lane; j < end; j += 64) {
        int s; float e;
        if (j < start + 64) { s = s_l; e = e_l; }
        else {
            s = csr_src[j];
            float t = as[s] + adv;
            e = t > 0.f ? t : LEAK * t;
        }
        float w = __expf(e - m);
        dsum += w;
        const float4* hp = (const float4*)&h2[s * 16];
        float4 v0 = hp[0], v1 = hp[1], v2 = hp[2], v3 = hp[3];
        acc[0] += w * v0.x; acc[1] += w * v0.y; acc[2] += w * v0.z; acc[3] += w * v0.w;
        acc[4] += w * v1.x; acc[5] += w * v1.y; acc[6] += w * v1.z; acc[7] += w * v1.w;
        acc[8] += w * v2.x; acc[9] += w * v2.y; acc[10] += w * v2.z; acc[11] += w * v2.w;
        acc[12] += w * v3.x; acc[13] += w * v3.y; acc[14] += w * v3.z; acc[15] += w * v3.w;
    }
#pragma unroll
    for (int off = 32; off; off >>= 1) {
        dsum += __shfl_xor(dsum, off);
#pragma unroll
        for (int f = 0; f < 16; ++f) acc[f] += __shfl_xor(acc[f], off);
    }
    if (lane == 0) {
        float inv = 1.0f / dsum;
        const float4* b4 = (const float4*)bias;
        float4 o0, o1, o2, o3;
        float4 bb0 = b4[0], bb1 = b4[1], bb2 = b4[2], bb3 = b4[3];
        o0.x = acc[0] * inv + bb0.x; o0.y = acc[1] * inv + bb0.y; o0.z = acc[2] * inv + bb0.z; o0.w = acc[3] * inv + bb0.w;
        o1.x = acc[4] * inv + bb1.x; o1.y = acc[5] * inv + bb1.y; o1.z = acc[6] * inv + bb1.z; o1.w = acc[7] * inv + bb1.w;
        o2.x = acc[8] * inv + bb2.x; o2.y = acc[9] * inv + bb2.y; o2.z = acc[10] * inv + bb2.z; o2.w = acc[11] * inv + bb2.w;
        o3.x = acc[12] * inv + bb3.x; o3.y = acc[13] * inv + bb3.y; o3.z = acc[14] * inv + bb3.w == 0.f ? acc[14] * inv + bb3.z : acc[14] * inv + bb3.z; o3.w = acc[15] * inv + bb3.w;
        // (typo-proof rewrite below)
        o3.x = acc[12] * inv + bb3.x; o3.y = acc[13] * inv + bb3.y; o3.z = acc[14] * inv + bb3.z; o3.w = acc[15] * inv + bb3.w;
        float4* op = (float4*)&out[wid * 16];
        op[0] = o0; op[1] = o1; op[2] = o2; op[3] = o3;
    }
}

extern "C" void kernel_launch(void* const* d_in, const int* in_sizes, int n_in,
                              void* d_out, int out_size, void* d_ws, size_t ws_size,
                              hipStream_t stream) {
    const float* x    = (const float*)d_in[0];
    const int*   ei   = (const int*)d_in[1];
    const float* W1   = (const float*)d_in[2];
    const float* avs1 = (const float*)d_in[3];
    const float* avd1 = (const float*)d_in[4];
    const float* b1   = (const float*)d_in[5];
    const float* W2   = (const float*)d_in[6];
    const float* avs2 = (const float*)d_in[7];
    const float* avd2 = (const float*)d_in[8];
    const float* b2   = (const float*)d_in[9];

    int N = in_sizes[0] / 128;
    int E = in_sizes[1] / 2;
    const int* esrc = ei;
    const int* edst = ei + E;
    int T = E + N;

    char* p = (char*)d_ws;
    auto carve = [&](size_t bytes) { char* r = p; p += align256(bytes); return r; };
    float* h1     = (float*)carve(sizeof(float) * (size_t)N * 128);
    float* agg1   = (float*)carve(sizeof(float) * (size_t)N * 128);
    float* h2     = (float*)carve(sizeof(float) * (size_t)N * 16);
    float* as1    = (float*)carve(sizeof(float) * N);
    float* ad1    = (float*)carve(sizeof(float) * N);
    float* as2    = (float*)carve(sizeof(float) * N);
    float* ad2    = (float*)carve(sizeof(float) * N);
    int* rowptr   = (int*)carve(sizeof(int) * (N + 1));
    int* degcur   = (int*)carve(sizeof(int) * 2 * (size_t)N);
    int* deg = degcur; int* cursor = degcur + N;
    int* csr_src  = (int*)carve(sizeof(int) * (size_t)T);

    hipMemsetAsync(degcur, 0, sizeof(int) * 2 * (size_t)N, stream);
    k_count<<<2048, 256, 0, stream>>>(edst, E, N, deg);
    k_scan<<<1, 1024, 0, stream>>>(deg, N, rowptr);
    k_scatter<<<2048, 256, 0, stream>>>(esrc, edst, E, N, rowptr, cursor, csr_src);

    int gGemm = (N + 31) / 32;
    k_gemm128<<<gGemm, 256, 0, stream>>>(x, W1, h1, N);
    int gWave = (N * 64 + 255) / 256;
    k_alpha128<<<gWave, 256, 0, stream>>>(h1, avs1, avd1, as1, ad1, N);
    k_agg128<<<gWave, 256, 0, stream>>>(h1, as1, ad1, b1, rowptr, csr_src, agg1, N);
    k_gemm16<<<gWave, 256, 0, stream>>>(agg1, W2, avs2, avd2, h2, as2, ad2, N);
    k_agg16<<<gWave, 256, 0, stream>>>(h2, as2, ad2, b2, rowptr, csr_src, (float*)d_out, N);
}

// Round 2
// 291.641 us; speedup vs baseline: 1.2497x; 1.2497x over previous
//
#include <hip/hip_runtime.h>

#define LEAK 0.2f

static inline size_t align256(size_t x) { return (x + 255) & ~size_t(255); }

// ---------------- CSR build ----------------
__global__ void k_count(const int* __restrict__ edst, int E, int N, int* __restrict__ deg) {
    int total = E + N;
    for (int k = blockIdx.x * blockDim.x + threadIdx.x; k < total; k += gridDim.x * blockDim.x) {
        int d = (k < E) ? edst[k] : (k - E);
        atomicAdd(&deg[d], 1);
    }
}

// ---- hierarchical scan: phase 1 — per-256-chunk sums ----
__global__ __launch_bounds__(256) void k_scan_partial(const int* __restrict__ deg, int N,
                                                      int* __restrict__ partial) {
    __shared__ int red[4];
    int i = blockIdx.x * 256 + threadIdx.x;
    int v = (i < N) ? deg[i] : 0;
#pragma unroll
    for (int off = 32; off; off >>= 1) v += __shfl_xor(v, off);
    int lane = threadIdx.x & 63, w = threadIdx.x >> 6;
    if (lane == 0) red[w] = v;
    __syncthreads();
    if (threadIdx.x == 0) partial[blockIdx.x] = red[0] + red[1] + red[2] + red[3];
}

// ---- phase 2 — single small block scans the partials (B <= 1024) ----
__global__ __launch_bounds__(1024) void k_scan_top(int* __restrict__ partial, int B) {
    __shared__ int buf[1024];
    int tid = threadIdx.x;
    int v = (tid < B) ? partial[tid] : 0;
    buf[tid] = v;
    __syncthreads();
    for (int off = 1; off < 1024; off <<= 1) {
        int t = buf[tid];
        int add = (tid >= off) ? buf[tid - off] : 0;
        __syncthreads();
        buf[tid] = t + add;
        __syncthreads();
    }
    // write EXCLUSIVE prefix back
    if (tid < B) partial[tid] = buf[tid] - v;
}

// ---- phase 3 — per-chunk inclusive scan + chunk offset -> rowptr ----
__global__ __launch_bounds__(256) void k_scan_final(const int* __restrict__ deg, int N,
                                                    const int* __restrict__ partial,
                                                    int* __restrict__ rowptr) {
    __shared__ int buf[256];
    int tid = threadIdx.x;
    int i = blockIdx.x * 256 + tid;
    int v = (i < N) ? deg[i] : 0;
    buf[tid] = v;
    __syncthreads();
    for (int off = 1; off < 256; off <<= 1) {
        int t = buf[tid];
        int add = (tid >= off) ? buf[tid - off] : 0;
        __syncthreads();
        buf[tid] = t + add;
        __syncthreads();
    }
    if (i < N) rowptr[i + 1] = partial[blockIdx.x] + buf[tid];
    if (i == 0) rowptr[0] = 0;
}

__global__ void k_scatter(const int* __restrict__ esrc, const int* __restrict__ edst,
                          int E, int N, const int* __restrict__ rowptr,
                          int* __restrict__ cursor, int* __restrict__ csr_src) {
    int total = E + N;
    for (int k = blockIdx.x * blockDim.x + threadIdx.x; k < total; k += gridDim.x * blockDim.x) {
        int s, d;
        if (k < E) { s = esrc[k]; d = edst[k]; } else { s = d = k - E; }
        int pos = atomicAdd(&cursor[d], 1);
        csr_src[rowptr[d] + pos] = s;
    }
}

// ---------------- GEMM: h[N,128] = x[N,128] @ W[128,128] ----------------
__global__ __launch_bounds__(256) void k_gemm128(const float* __restrict__ x,
                                                 const float* __restrict__ W,
                                                 float* __restrict__ h, int N) {
    __shared__ float sW[128 * 128];
    __shared__ float sX[32 * 128];
    int tid = threadIdx.x;
    const float4* W4 = (const float4*)W;
    float4* sW4 = (float4*)sW;
#pragma unroll
    for (int i = 0; i < 16; ++i) sW4[tid + i * 256] = W4[tid + i * 256];

    int row0 = blockIdx.x * 32;
    int lr = tid >> 5;       // 0..7
    int lk = tid & 31;       // float4 index within row
    const float4* x4 = (const float4*)x;
    float4* sX4 = (float4*)sX;
#pragma unroll
    for (int i = 0; i < 4; ++i) {
        int r = lr + i * 8;
        int gr = row0 + r; if (gr > N - 1) gr = N - 1;
        sX4[r * 32 + lk] = x4[gr * 32 + lk];
    }
    __syncthreads();

    int tr = (tid >> 5) * 4;    // 4 rows
    int tc = (tid & 31) * 4;    // 4 cols
    float acc[4][4] = {};
#pragma unroll 4
    for (int k = 0; k < 128; ++k) {
        float4 w = *(const float4*)&sW[k * 128 + tc];
#pragma unroll
        for (int i = 0; i < 4; ++i) {
            float xv = sX[(tr + i) * 128 + k];
            acc[i][0] += xv * w.x; acc[i][1] += xv * w.y;
            acc[i][2] += xv * w.z; acc[i][3] += xv * w.w;
        }
    }
#pragma unroll
    for (int i = 0; i < 4; ++i) {
        int gr = row0 + tr + i;
        if (gr < N) {
            float4 o; o.x = acc[i][0]; o.y = acc[i][1]; o.z = acc[i][2]; o.w = acc[i][3];
            *(float4*)&h[gr * 128 + tc] = o;
        }
    }
}

// ---------------- alphas (one wave/node) ----------------
__global__ __launch_bounds__(256) void k_alpha128(const float* __restrict__ h,
                                                  const float* __restrict__ avs,
                                                  const float* __restrict__ avd,
                                                  float* __restrict__ as, float* __restrict__ ad, int N) {
    int wid = (blockIdx.x * blockDim.x + threadIdx.x) >> 6;
    int lane = threadIdx.x & 63;
    if (wid >= N) return;
    float h0 = h[wid * 128 + lane], h1 = h[wid * 128 + 64 + lane];
    float ps = h0 * avs[lane] + h1 * avs[64 + lane];
    float pd = h0 * avd[lane] + h1 * avd[64 + lane];
#pragma unroll
    for (int off = 32; off; off >>= 1) {
        ps += __shfl_xor(ps, off);
        pd += __shfl_xor(pd, off);
    }
    if (lane == 0) { as[wid] = ps; ad[wid] = pd; }
}

// ---------------- layer-1 aggregation (128 feats, one wave per dst node) ----------------
__global__ __launch_bounds__(256) void k_agg128(const float* __restrict__ h,
                                                const float* __restrict__ as,
                                                const float* __restrict__ ad,
                                                const float* __restrict__ bias,
                                                const int* __restrict__ rowptr,
                                                const int* __restrict__ csr_src,
                                                float* __restrict__ out, int N) {
    int wid = (blockIdx.x * blockDim.x + threadIdx.x) >> 6;
    int lane = threadIdx.x & 63;
    if (wid >= N) return;
    int start = rowptr[wid], end = rowptr[wid + 1];
    int deg = end - start;
    float adv = ad[wid];

    int s_l = 0; float e_l = -1e30f;
    if (lane < deg) {
        s_l = csr_src[start + lane];
        float e = as[s_l] + adv;
        e_l = e > 0.f ? e : LEAK * e;
    }
    float m = e_l;
    for (int j = start + 64 + lane; j < end; j += 64) {
        int s = csr_src[j];
        float e = as[s] + adv;
        e = e > 0.f ? e : LEAK * e;
        m = fmaxf(m, e);
    }
#pragma unroll
    for (int off = 32; off; off >>= 1) m = fmaxf(m, __shfl_xor(m, off));

    float acc0 = 0.f, acc1 = 0.f, denom = 0.f;
    int dmain = deg < 64 ? deg : 64;
    for (int j = 0; j < dmain; ++j) {
        int s = __shfl(s_l, j);
        float e = __shfl(e_l, j);
        float w = __expf(e - m);
        denom += w;
        acc0 += w * h[s * 128 + lane];
        acc1 += w * h[s * 128 + 64 + lane];
    }
    for (int j = start + 64; j < end; ++j) {
        int s = csr_src[j];  // wave-uniform
        float e = as[s] + adv;
        e = e > 0.f ? e : LEAK * e;
        float w = __expf(e - m);
        denom += w;
        acc0 += w * h[s * 128 + lane];
        acc1 += w * h[s * 128 + 64 + lane];
    }
    float inv = 1.0f / denom;
    float o0 = acc0 * inv + bias[lane];
    float o1 = acc1 * inv + bias[64 + lane];
    out[wid * 128 + lane]      = fmaxf(o0, 0.f);   // fused ReLU (layer 1)
    out[wid * 128 + 64 + lane] = fmaxf(o1, 0.f);
}

// ------- h2[N,16] = g[N,128] @ W2[128,16], fused alpha2 dots (one wave/node) -------
__global__ __launch_bounds__(256) void k_gemm16(const float* __restrict__ g,
                                                const float* __restrict__ W2,
                                                const float* __restrict__ avs,
                                                const float* __restrict__ avd,
                                                float* __restrict__ h2,
                                                float* __restrict__ as2, float* __restrict__ ad2, int N) {
    int wid = (blockIdx.x * blockDim.x + threadIdx.x) >> 6;
    int lane = threadIdx.x & 63;
    if (wid >= N) return;
    int col = lane & 15, kg = lane >> 4;   // 4 k-groups x 32
    float acc = 0.f;
#pragma unroll
    for (int kk = 0; kk < 32; ++kk) {
        int k = kg * 32 + kk;
        acc += g[wid * 128 + k] * W2[k * 16 + col];
    }
    acc += __shfl_xor(acc, 16);
    acc += __shfl_xor(acc, 32);          // all lanes: h2 value for their col
    if (lane < 16) h2[wid * 16 + col] = acc;
    float ps = acc * avs[col];
    float pd = acc * avd[col];
#pragma unroll
    for (int off = 8; off; off >>= 1) {
        ps += __shfl_xor(ps, off);
        pd += __shfl_xor(pd, off);
    }
    if (lane == 0) { as2[wid] = ps; ad2[wid] = pd; }
}

// ---------------- layer-2 aggregation (16 feats, edge-parallel per wave) ----------------
__global__ __launch_bounds__(256) void k_agg16(const float* __restrict__ h2,
                                               const float* __restrict__ as,
                                               const float* __restrict__ ad,
                                               const float* __restrict__ bias,
                                               const int* __restrict__ rowptr,
                                               const int* __restrict__ csr_src,
                                               float* __restrict__ out, int N) {
    int wid = (blockIdx.x * blockDim.x + threadIdx.x) >> 6;
    int lane = threadIdx.x & 63;
    if (wid >= N) return;
    int start = rowptr[wid], end = rowptr[wid + 1];
    float adv = ad[wid];

    int s_l = 0; float e_l = -1e30f;
    if (start + lane < end) {
        s_l = csr_src[start + lane];
        float e = as[s_l] + adv;
        e_l = e > 0.f ? e : LEAK * e;
    }
    float m = e_l;
    for (int j = start + 64 + lane; j < end; j += 64) {
        int s = csr_src[j];
        float e = as[s] + adv;
        e = e > 0.f ? e : LEAK * e;
        m = fmaxf(m, e);
    }
#pragma unroll
    for (int off = 32; off; off >>= 1) m = fmaxf(m, __shfl_xor(m, off));

    float acc[16];
#pragma unroll
    for (int f = 0; f < 16; ++f) acc[f] = 0.f;
    float dsum = 0.f;
    for (int j = start + lane; j < end; j += 64) {
        int s; float e;
        if (j < start + 64) { s = s_l; e = e_l; }
        else {
            s = csr_src[j];
            float t = as[s] + adv;
            e = t > 0.f ? t : LEAK * t;
        }
        float w = __expf(e - m);
        dsum += w;
        const float4* hp = (const float4*)&h2[s * 16];
        float4 v0 = hp[0], v1 = hp[1], v2 = hp[2], v3 = hp[3];
        acc[0] += w * v0.x; acc[1] += w * v0.y; acc[2] += w * v0.z; acc[3] += w * v0.w;
        acc[4] += w * v1.x; acc[5] += w * v1.y; acc[6] += w * v1.z; acc[7] += w * v1.w;
        acc[8] += w * v2.x; acc[9] += w * v2.y; acc[10] += w * v2.z; acc[11] += w * v2.w;
        acc[12] += w * v3.x; acc[13] += w * v3.y; acc[14] += w * v3.z; acc[15] += w * v3.w;
    }
#pragma unroll
    for (int off = 32; off; off >>= 1) {
        dsum += __shfl_xor(dsum, off);
#pragma unroll
        for (int f = 0; f < 16; ++f) acc[f] += __shfl_xor(acc[f], off);
    }
    if (lane == 0) {
        float inv = 1.0f / dsum;
        const float4* b4 = (const float4*)bias;
        float4 bb0 = b4[0], bb1 = b4[1], bb2 = b4[2], bb3 = b4[3];
        float4 o0, o1, o2, o3;
        o0.x = acc[0] * inv + bb0.x; o0.y = acc[1] * inv + bb0.y; o0.z = acc[2] * inv + bb0.z; o0.w = acc[3] * inv + bb0.w;
        o1.x = acc[4] * inv + bb1.x; o1.y = acc[5] * inv + bb1.y; o1.z = acc[6] * inv + bb1.z; o1.w = acc[7] * inv + bb1.w;
        o2.x = acc[8] * inv + bb2.x; o2.y = acc[9] * inv + bb2.y; o2.z = acc[10] * inv + bb2.z; o2.w = acc[11] * inv + bb2.w;
        o3.x = acc[12] * inv + bb3.x; o3.y = acc[13] * inv + bb3.y; o3.z = acc[14] * inv + bb3.z; o3.w = acc[15] * inv + bb3.w;
        float4* op = (float4*)&out[wid * 16];
        op[0] = o0; op[1] = o1; op[2] = o2; op[3] = o3;
    }
}

extern "C" void kernel_launch(void* const* d_in, const int* in_sizes, int n_in,
                              void* d_out, int out_size, void* d_ws, size_t ws_size,
                              hipStream_t stream) {
    const float* x    = (const float*)d_in[0];
    const int*   ei   = (const int*)d_in[1];
    const float* W1   = (const float*)d_in[2];
    const float* avs1 = (const float*)d_in[3];
    const float* avd1 = (const float*)d_in[4];
    const float* b1   = (const float*)d_in[5];
    const float* W2   = (const float*)d_in[6];
    const float* avs2 = (const float*)d_in[7];
    const float* avd2 = (const float*)d_in[8];
    const float* b2   = (const float*)d_in[9];

    int N = in_sizes[0] / 128;
    int E = in_sizes[1] / 2;
    const int* esrc = ei;
    const int* edst = ei + E;
    int T = E + N;

    char* p = (char*)d_ws;
    auto carve = [&](size_t bytes) { char* r = p; p += align256(bytes); return r; };
    float* h1     = (float*)carve(sizeof(float) * (size_t)N * 128);
    float* agg1   = (float*)carve(sizeof(float) * (size_t)N * 128);
    float* h2     = (float*)carve(sizeof(float) * (size_t)N * 16);
    float* as1    = (float*)carve(sizeof(float) * N);
    float* ad1    = (float*)carve(sizeof(float) * N);
    float* as2    = (float*)carve(sizeof(float) * N);
    float* ad2    = (float*)carve(sizeof(float) * N);
    int* rowptr   = (int*)carve(sizeof(int) * (N + 1));
    int* degcur   = (int*)carve(sizeof(int) * 2 * (size_t)N);
    int* deg = degcur; int* cursor = degcur + N;
    int* partial  = (int*)carve(sizeof(int) * 1024);
    int* csr_src  = (int*)carve(sizeof(int) * (size_t)T);

    hipMemsetAsync(degcur, 0, sizeof(int) * 2 * (size_t)N, stream);
    k_count<<<2048, 256, 0, stream>>>(edst, E, N, deg);

    int B = (N + 255) / 256;                 // 196 chunks for N=50000 (B <= 1024 assumed)
    k_scan_partial<<<B, 256, 0, stream>>>(deg, N, partial);
    k_scan_top<<<1, 1024, 0, stream>>>(partial, B);
    k_scan_final<<<B, 256, 0, stream>>>(deg, N, partial, rowptr);

    k_scatter<<<2048, 256, 0, stream>>>(esrc, edst, E, N, rowptr, cursor, csr_src);

    int gGemm = (N + 31) / 32;
    k_gemm128<<<gGemm, 256, 0, stream>>>(x, W1, h1, N);
    int gWave = (N * 64 + 255) / 256;
    k_alpha128<<<gWave, 256, 0, stream>>>(h1, avs1, avd1, as1, ad1, N);
    k_agg128<<<gWave, 256, 0, stream>>>(h1, as1, ad1, b1, rowptr, csr_src, agg1, N);
    k_gemm16<<<gWave, 256, 0, stream>>>(agg1, W2, avs2, avd2, h2, as2, ad2, N);
    k_agg16<<<gWave, 256, 0, stream>>>(h2, as2, ad2, b2, rowptr, csr_src, (float*)d_out, N);
}

// Round 3
// 241.620 us; speedup vs baseline: 1.5084x; 1.2070x over previous
//
#include <hip/hip_runtime.h>

#define LEAK 0.2f

static inline size_t align256(size_t x) { return (x + 255) & ~size_t(255); }

// ---------------- CSR build ----------------
__global__ void k_count(const int* __restrict__ edst, int E, int N, int* __restrict__ deg) {
    int total = E + N;
    for (int k = blockIdx.x * blockDim.x + threadIdx.x; k < total; k += gridDim.x * blockDim.x) {
        int d = (k < E) ? edst[k] : (k - E);
        atomicAdd(&deg[d], 1);
    }
}

// ---- hierarchical scan: phase 1 — per-256-chunk sums ----
__global__ __launch_bounds__(256) void k_scan_partial(const int* __restrict__ deg, int N,
                                                      int* __restrict__ partial) {
    __shared__ int red[4];
    int i = blockIdx.x * 256 + threadIdx.x;
    int v = (i < N) ? deg[i] : 0;
#pragma unroll
    for (int off = 32; off; off >>= 1) v += __shfl_xor(v, off);
    int lane = threadIdx.x & 63, w = threadIdx.x >> 6;
    if (lane == 0) red[w] = v;
    __syncthreads();
    if (threadIdx.x == 0) partial[blockIdx.x] = red[0] + red[1] + red[2] + red[3];
}

// ---- phase 2 — single small block scans the partials (B <= 1024) ----
__global__ __launch_bounds__(1024) void k_scan_top(int* __restrict__ partial, int B) {
    __shared__ int buf[1024];
    int tid = threadIdx.x;
    int v = (tid < B) ? partial[tid] : 0;
    buf[tid] = v;
    __syncthreads();
    for (int off = 1; off < 1024; off <<= 1) {
        int t = buf[tid];
        int add = (tid >= off) ? buf[tid - off] : 0;
        __syncthreads();
        buf[tid] = t + add;
        __syncthreads();
    }
    if (tid < B) partial[tid] = buf[tid] - v;   // exclusive
}

// ---- phase 3 — per-chunk inclusive scan + chunk offset -> rowptr ----
__global__ __launch_bounds__(256) void k_scan_final(const int* __restrict__ deg, int N,
                                                    const int* __restrict__ partial,
                                                    int* __restrict__ rowptr) {
    __shared__ int buf[256];
    int tid = threadIdx.x;
    int i = blockIdx.x * 256 + tid;
    int v = (i < N) ? deg[i] : 0;
    buf[tid] = v;
    __syncthreads();
    for (int off = 1; off < 256; off <<= 1) {
        int t = buf[tid];
        int add = (tid >= off) ? buf[tid - off] : 0;
        __syncthreads();
        buf[tid] = t + add;
        __syncthreads();
    }
    if (i < N) rowptr[i + 1] = partial[blockIdx.x] + buf[tid];
    if (i == 0) rowptr[0] = 0;
}

__global__ void k_scatter(const int* __restrict__ esrc, const int* __restrict__ edst,
                          int E, int N, const int* __restrict__ rowptr,
                          int* __restrict__ cursor, int* __restrict__ csr_src) {
    int total = E + N;
    for (int k = blockIdx.x * blockDim.x + threadIdx.x; k < total; k += gridDim.x * blockDim.x) {
        int s, d;
        if (k < E) { s = esrc[k]; d = edst[k]; } else { s = d = k - E; }
        int pos = atomicAdd(&cursor[d], 1);
        csr_src[rowptr[d] + pos] = s;
    }
}

// ------- GEMM: h[N,128] = x[N,128] @ W[128,128], fused alpha1 dots -------
__global__ __launch_bounds__(256) void k_gemm128(const float* __restrict__ x,
                                                 const float* __restrict__ W,
                                                 const float* __restrict__ avs,
                                                 const float* __restrict__ avd,
                                                 float* __restrict__ h,
                                                 float* __restrict__ as, float* __restrict__ ad,
                                                 int N) {
    __shared__ float sW[128 * 128];
    __shared__ float sX[32 * 128];
    int tid = threadIdx.x;
    const float4* W4 = (const float4*)W;
    float4* sW4 = (float4*)sW;
#pragma unroll
    for (int i = 0; i < 16; ++i) sW4[tid + i * 256] = W4[tid + i * 256];

    int row0 = blockIdx.x * 32;
    int lr = tid >> 5;       // 0..7
    int lk = tid & 31;       // float4 index within row
    const float4* x4 = (const float4*)x;
    float4* sX4 = (float4*)sX;
#pragma unroll
    for (int i = 0; i < 4; ++i) {
        int r = lr + i * 8;
        int gr = row0 + r; if (gr > N - 1) gr = N - 1;
        sX4[r * 32 + lk] = x4[gr * 32 + lk];
    }
    __syncthreads();

    int tr = (tid >> 5) * 4;    // 4 rows
    int tc = (tid & 31) * 4;    // 4 cols
    float acc[4][4] = {};
#pragma unroll 4
    for (int k = 0; k < 128; ++k) {
        float4 w = *(const float4*)&sW[k * 128 + tc];
#pragma unroll
        for (int i = 0; i < 4; ++i) {
            float xv = sX[(tr + i) * 128 + k];
            acc[i][0] += xv * w.x; acc[i][1] += xv * w.y;
            acc[i][2] += xv * w.z; acc[i][3] += xv * w.w;
        }
    }
    float4 vs = *(const float4*)&avs[tc];
    float4 vd = *(const float4*)&avd[tc];
#pragma unroll
    for (int i = 0; i < 4; ++i) {
        int gr = row0 + tr + i;
        if (gr < N) {
            float4 o; o.x = acc[i][0]; o.y = acc[i][1]; o.z = acc[i][2]; o.w = acc[i][3];
            *(float4*)&h[gr * 128 + tc] = o;
        }
        // alpha dots: reduce over the 32 col-threads (same 32-lane half)
        float ps = acc[i][0]*vs.x + acc[i][1]*vs.y + acc[i][2]*vs.z + acc[i][3]*vs.w;
        float pd = acc[i][0]*vd.x + acc[i][1]*vd.y + acc[i][2]*vd.z + acc[i][3]*vd.w;
#pragma unroll
        for (int off = 16; off; off >>= 1) {
            ps += __shfl_xor(ps, off);
            pd += __shfl_xor(pd, off);
        }
        if ((tid & 31) == 0 && gr < N) { as[gr] = ps; ad[gr] = pd; }
    }
}

// ---- layer-1 aggregation + ReLU + GEMM16 + alpha2, one wave per dst node ----
__global__ __launch_bounds__(256) void k_agg128f(const float* __restrict__ h,
                                                 const float* __restrict__ as,
                                                 const float* __restrict__ ad,
                                                 const float* __restrict__ b1,
                                                 const float* __restrict__ W2,
                                                 const float* __restrict__ avs2,
                                                 const float* __restrict__ avd2,
                                                 const int* __restrict__ rowptr,
                                                 const int* __restrict__ csr_src,
                                                 float* __restrict__ h2,
                                                 float* __restrict__ as2, float* __restrict__ ad2,
                                                 int N) {
    __shared__ float gbuf[4][128];
    int wid = (blockIdx.x * blockDim.x + threadIdx.x) >> 6;
    int lane = threadIdx.x & 63;
    int wib = threadIdx.x >> 6;
    if (wid >= N) return;
    int start = rowptr[wid], end = rowptr[wid + 1];
    int deg = end - start;
    float adv = ad[wid];

    int s_l = 0; float e_l = -1e30f;
    if (lane < deg) {
        s_l = csr_src[start + lane];
        float e = as[s_l] + adv;
        e_l = e > 0.f ? e : LEAK * e;
    }
    float m = e_l;
    for (int j = start + 64 + lane; j < end; j += 64) {
        int s = csr_src[j];
        float e = as[s] + adv;
        e = e > 0.f ? e : LEAK * e;
        m = fmaxf(m, e);
    }
#pragma unroll
    for (int off = 32; off; off >>= 1) m = fmaxf(m, __shfl_xor(m, off));

    const float2* hrow = (const float2*)h;     // rows of 64 float2
    float2 accv = make_float2(0.f, 0.f);
    float denom = 0.f;
    int dmain = deg < 64 ? deg : 64;
    for (int j = 0; j < dmain; ++j) {
        int s = __shfl(s_l, j);
        float e = __shfl(e_l, j);
        float w = __expf(e - m);
        denom += w;
        float2 hv = hrow[s * 64 + lane];
        accv.x += w * hv.x; accv.y += w * hv.y;
    }
    for (int j = start + 64; j < end; ++j) {
        int s = csr_src[j];  // wave-uniform
        float e = as[s] + adv;
        e = e > 0.f ? e : LEAK * e;
        float w = __expf(e - m);
        denom += w;
        float2 hv = hrow[s * 64 + lane];
        accv.x += w * hv.x; accv.y += w * hv.y;
    }
    float inv = 1.0f / denom;
    float2 bb = ((const float2*)b1)[lane];
    float gx = fmaxf(accv.x * inv + bb.x, 0.f);   // fused ReLU
    float gy = fmaxf(accv.y * inv + bb.y, 0.f);
    ((float2*)gbuf[wib])[lane] = make_float2(gx, gy);

    // h2 row = g @ W2 (128x16): lane = (q<<4)|c, k = kk*4+q keeps LDS banks distinct
    int q = lane >> 4, c = lane & 15;
    float p = 0.f;
#pragma unroll
    for (int kk = 0; kk < 32; ++kk) {
        int k = kk * 4 + q;
        p += gbuf[wib][k] * W2[k * 16 + c];
    }
    p += __shfl_xor(p, 16);
    p += __shfl_xor(p, 32);          // all lanes: h2 value for col c
    if (lane < 16) h2[wid * 16 + c] = p;
    float ps = p * avs2[c];
    float pd = p * avd2[c];
#pragma unroll
    for (int off = 8; off; off >>= 1) {
        ps += __shfl_xor(ps, off);
        pd += __shfl_xor(pd, off);
    }
    if (lane == 0) { as2[wid] = ps; ad2[wid] = pd; }
}

// ---- layer-2 aggregation: 16 lanes per node, serial over edges, no shuffles ----
__global__ __launch_bounds__(256) void k_agg16(const float* __restrict__ h2,
                                               const float* __restrict__ as,
                                               const float* __restrict__ ad,
                                               const float* __restrict__ bias,
                                               const int* __restrict__ rowptr,
                                               const int* __restrict__ csr_src,
                                               float* __restrict__ out, int N) {
    int grp = (blockIdx.x * blockDim.x + threadIdx.x) >> 4;  // node id
    int c = threadIdx.x & 15;
    if (grp >= N) return;
    int start = rowptr[grp], end = rowptr[grp + 1];
    float adv = ad[grp];
    float m = -1e30f;
    for (int j = start; j < end; ++j) {
        int s = csr_src[j];                      // broadcast across 16 lanes
        float e = as[s] + adv;
        e = e > 0.f ? e : LEAK * e;
        m = fmaxf(m, e);
    }
    float acc = 0.f, dsum = 0.f;
    for (int j = start; j < end; ++j) {
        int s = csr_src[j];
        float e = as[s] + adv;
        e = e > 0.f ? e : LEAK * e;
        float w = __expf(e - m);
        dsum += w;
        acc += w * h2[s * 16 + c];
    }
    out[grp * 16 + c] = acc / dsum + bias[c];
}

extern "C" void kernel_launch(void* const* d_in, const int* in_sizes, int n_in,
                              void* d_out, int out_size, void* d_ws, size_t ws_size,
                              hipStream_t stream) {
    const float* x    = (const float*)d_in[0];
    const int*   ei   = (const int*)d_in[1];
    const float* W1   = (const float*)d_in[2];
    const float* avs1 = (const float*)d_in[3];
    const float* avd1 = (const float*)d_in[4];
    const float* b1   = (const float*)d_in[5];
    const float* W2   = (const float*)d_in[6];
    const float* avs2 = (const float*)d_in[7];
    const float* avd2 = (const float*)d_in[8];
    const float* b2   = (const float*)d_in[9];

    int N = in_sizes[0] / 128;
    int E = in_sizes[1] / 2;
    const int* esrc = ei;
    const int* edst = ei + E;
    int T = E + N;

    char* p = (char*)d_ws;
    auto carve = [&](size_t bytes) { char* r = p; p += align256(bytes); return r; };
    float* h1     = (float*)carve(sizeof(float) * (size_t)N * 128);
    float* h2     = (float*)carve(sizeof(float) * (size_t)N * 16);
    float* as1    = (float*)carve(sizeof(float) * N);
    float* ad1    = (float*)carve(sizeof(float) * N);
    float* as2    = (float*)carve(sizeof(float) * N);
    float* ad2    = (float*)carve(sizeof(float) * N);
    int* rowptr   = (int*)carve(sizeof(int) * (N + 1));
    int* degcur   = (int*)carve(sizeof(int) * 2 * (size_t)N);
    int* deg = degcur; int* cursor = degcur + N;
    int* partial  = (int*)carve(sizeof(int) * 1024);
    int* csr_src  = (int*)carve(sizeof(int) * (size_t)T);

    hipMemsetAsync(degcur, 0, sizeof(int) * 2 * (size_t)N, stream);
    k_count<<<2048, 256, 0, stream>>>(edst, E, N, deg);

    int B = (N + 255) / 256;                 // 196 for N=50000 (B <= 1024 assumed)
    k_scan_partial<<<B, 256, 0, stream>>>(deg, N, partial);
    k_scan_top<<<1, 1024, 0, stream>>>(partial, B);
    k_scan_final<<<B, 256, 0, stream>>>(deg, N, partial, rowptr);

    k_scatter<<<2048, 256, 0, stream>>>(esrc, edst, E, N, rowptr, cursor, csr_src);

    int gGemm = (N + 31) / 32;
    k_gemm128<<<gGemm, 256, 0, stream>>>(x, W1, avs1, avd1, h1, as1, ad1, N);
    int gWave = (N * 64 + 255) / 256;
    k_agg128f<<<gWave, 256, 0, stream>>>(h1, as1, ad1, b1, W2, avs2, avd2,
                                         rowptr, csr_src, h2, as2, ad2, N);
    int gAgg16 = (N * 16 + 255) / 256;
    k_agg16<<<gAgg16, 256, 0, stream>>>(h2, as2, ad2, b2, rowptr, csr_src, (float*)d_out, N);
}